// Round 1
// baseline (670.052 us; speedup 1.0000x reference)
//
#include <hip/hip_runtime.h>
#include <math.h>

#define NH 32
#define NKVH 8
#define GRP 4
#define HD 128
#define LQB 128
#define PTSTRIDE 128
#define QK_SCALE 0.08838834764831845f

typedef __attribute__((ext_vector_type(8))) __bf16 bf16x8;
typedef __attribute__((ext_vector_type(4))) float f32x4;

static __device__ __forceinline__ bf16x8 cvt8s(const float* __restrict__ p, float s) {
    const float4 a = *reinterpret_cast<const float4*>(p);
    const float4 b = *reinterpret_cast<const float4*>(p + 4);
    bf16x8 r;
    r[0] = (__bf16)(a.x * s); r[1] = (__bf16)(a.y * s);
    r[2] = (__bf16)(a.z * s); r[3] = (__bf16)(a.w * s);
    r[4] = (__bf16)(b.x * s); r[5] = (__bf16)(b.y * s);
    r[6] = (__bf16)(b.z * s); r[7] = (__bf16)(b.w * s);
    return r;
}
static __device__ __forceinline__ bf16x8 cvt8(const float* __restrict__ p) {
    const float4 a = *reinterpret_cast<const float4*>(p);
    const float4 b = *reinterpret_cast<const float4*>(p + 4);
    bf16x8 r;
    r[0] = (__bf16)a.x; r[1] = (__bf16)a.y; r[2] = (__bf16)a.z; r[3] = (__bf16)a.w;
    r[4] = (__bf16)b.x; r[5] = (__bf16)b.y; r[6] = (__bf16)b.z; r[7] = (__bf16)b.w;
    return r;
}

// One wave: 16 q-rows of one head. One block (4 waves): the 4 heads of one kv-head
// group, same q-tile -> identical K/V stream and identical mask bound (no divergence).
// Swapped QK^T (S^T = K*Q^T) so softmax is lane-local + 2 shfl_xor; PV computed as
// O^T = V^T * P^T with matching slot conventions (robust to A/B k-slot permutation).
__global__ __launch_bounds__(256, 2)
void attn_fwd(const float* __restrict__ Q,
              const float* __restrict__ Kn,
              const float* __restrict__ Vn,
              const float* __restrict__ Kc,
              const float* __restrict__ Vc,
              const int* __restrict__ PT,
              const int* __restrict__ CTX,
              float* __restrict__ O)
{
    const int ctx  = CTX[0];                 // 2048
    const int tid  = (int)threadIdx.x;
    const int wave = tid >> 6;
    const int lane = tid & 63;
    const int low  = lane & 15;              // q column (C/D col) / A-frag row
    const int hi   = lane >> 4;              // lane group 0..3

    const int bid   = (int)blockIdx.x;
    const int qtile = bid & 7;
    const int kvh   = (bid >> 3) & 7;
    const int b     = bid >> 6;
    const int head  = kvh * GRP + wave;
    const int q0    = qtile * 16;

    const int qtok = b * LQB + q0 + low;
    const float* qrow = Q + (size_t)qtok * (NH * HD) + head * HD;

    // Q fragments (B-operand of QK^T), pre-scaled, d-slot = 32c + 8*hi + j
    bf16x8 qf[4];
    #pragma unroll
    for (int c = 0; c < 4; ++c)
        qf[c] = cvt8s(qrow + 32 * c + 8 * hi, QK_SCALE);

    f32x4 acc[8];                            // O^T accumulators, 8 d-chunks of 16
    #pragma unroll
    for (int c = 0; c < 8; ++c) acc[c] = (f32x4){0.f, 0.f, 0.f, 0.f};
    float mrun = -1e30f;
    float lrun = 0.f;

    // visible new keys for this q-tile: whole multiples of 32 -> no partial masks
    const int nb = (((q0 >> 5) + 1) << 5);
    const int nsteps = (ctx >> 5) + (nb >> 5);

    for (int s = 0; s < nsteps; ++s) {
        const int t0 = s << 5;
        const float* Kb;
        const float* Vb;
        int krow0, krow1, vrow[8];
        if (t0 < ctx) {                      // paged cache region (2 pages per step)
            Kb = Kc; Vb = Vc;
            const int pg0 = PT[b * PTSTRIDE + (t0 >> 4)];
            const int pg1 = PT[b * PTSTRIDE + (t0 >> 4) + 1];
            const int b0 = (pg0 * 16) * (NKVH * HD) + kvh * HD;
            const int b1 = (pg1 * 16) * (NKVH * HD) + kvh * HD;
            krow0 = b0 + low * (NKVH * HD);
            krow1 = b1 + low * (NKVH * HD);
            #pragma unroll
            for (int j = 0; j < 4; ++j) {
                vrow[j]     = b0 + (4 * hi + j) * (NKVH * HD);
                vrow[j + 4] = b1 + (4 * hi + j) * (NKVH * HD);
            }
        } else {                             // new-token region
            Kb = Kn; Vb = Vn;
            const int tn = t0 - ctx;
            const int base = (b * LQB + tn) * (NKVH * HD) + kvh * HD;
            krow0 = base + low * (NKVH * HD);
            krow1 = base + (16 + low) * (NKVH * HD);
            #pragma unroll
            for (int j = 0; j < 4; ++j) {
                vrow[j]     = base + (4 * hi + j) * (NKVH * HD);
                vrow[j + 4] = base + (16 + 4 * hi + j) * (NKVH * HD);
            }
        }

        // S^T tiles: C0 = keys t0..t0+15, C1 = keys t0+16..t0+31
        f32x4 s0 = (f32x4){0.f, 0.f, 0.f, 0.f};
        f32x4 s1 = (f32x4){0.f, 0.f, 0.f, 0.f};
        #pragma unroll
        for (int c = 0; c < 4; ++c) {
            bf16x8 ka = cvt8(Kb + krow0 + 32 * c + 8 * hi);
            bf16x8 kb = cvt8(Kb + krow1 + 32 * c + 8 * hi);
            s0 = __builtin_amdgcn_mfma_f32_16x16x32_bf16(ka, qf[c], s0, 0, 0, 0);
            s1 = __builtin_amdgcn_mfma_f32_16x16x32_bf16(kb, qf[c], s1, 0, 0, 0);
        }

        // online softmax: lane holds 8 scores for q=low, keys {4hi+r, 16+4hi+r}
        float pmax = fmaxf(fmaxf(fmaxf(s0[0], s0[1]), fmaxf(s0[2], s0[3])),
                           fmaxf(fmaxf(s1[0], s1[1]), fmaxf(s1[2], s1[3])));
        pmax = fmaxf(pmax, __shfl_xor(pmax, 16));
        pmax = fmaxf(pmax, __shfl_xor(pmax, 32));

        const float mnew = fmaxf(mrun, pmax);
        const float corr = __expf(mrun - mnew);
        mrun = mnew;

        float p[8];
        #pragma unroll
        for (int j = 0; j < 4; ++j) {
            p[j]     = __expf(s0[j] - mnew);
            p[j + 4] = __expf(s1[j] - mnew);
        }
        lrun = lrun * corr +
               (((p[0] + p[1]) + (p[2] + p[3])) + ((p[4] + p[5]) + (p[6] + p[7])));

        bf16x8 pf;                           // P^T B-fragment, slot j <-> key kappa(hi,j)
        #pragma unroll
        for (int j = 0; j < 8; ++j) pf[j] = (__bf16)p[j];

        #pragma unroll
        for (int c = 0; c < 8; ++c) acc[c] *= corr;

        // PV: A-operand = V^T, slot j reads V[kappa(hi,j)][16c + low]
        #pragma unroll
        for (int c = 0; c < 8; ++c) {
            bf16x8 vf;
            #pragma unroll
            for (int j = 0; j < 8; ++j)
                vf[j] = (__bf16)Vb[vrow[j] + 16 * c + low];
            acc[c] = __builtin_amdgcn_mfma_f32_16x16x32_bf16(vf, pf, acc[c], 0, 0, 0);
        }
    }

    // finish: reduce l across the 4 lanes sharing q, normalize, store O[q][d]
    lrun += __shfl_xor(lrun, 16);
    lrun += __shfl_xor(lrun, 32);
    const float inv = 1.0f / lrun;

    float* orow = O + (size_t)qtok * (NH * HD) + head * HD;
    #pragma unroll
    for (int c = 0; c < 8; ++c) {
        f32x4 r = acc[c] * inv;
        *reinterpret_cast<f32x4*>(orow + 16 * c + 4 * hi) = r;
    }
}

extern "C" void kernel_launch(void* const* d_in, const int* in_sizes, int n_in,
                              void* d_out, int out_size, void* d_ws, size_t ws_size,
                              hipStream_t stream) {
    const float* q  = (const float*)d_in[0];
    const float* k  = (const float*)d_in[1];
    const float* v  = (const float*)d_in[2];
    const float* kc = (const float*)d_in[3];
    const float* vc = (const float*)d_in[4];
    const int*   pt = (const int*)d_in[5];
    const int*   cx = (const int*)d_in[6];
    float* out = (float*)d_out;

    // grid: 8 seqs * 8 kv-heads * 8 q-tiles; block: 4 waves = 4 heads of the group
    attn_fwd<<<dim3(512), dim3(256), 0, stream>>>(q, k, v, kc, vc, pt, cx, out);
}

// Round 2
// 272.977 us; speedup vs baseline: 2.4546x; 2.4546x over previous
//
#include <hip/hip_runtime.h>
#include <math.h>

#define NH 32
#define NKVH 8
#define GRP 4
#define HD 128
#define LQB 128
#define PTSTRIDE 128
#define KVROW (NKVH * HD)          // 1024 floats per token row
#define QK_SCALE 0.08838834764831845f

typedef __attribute__((ext_vector_type(8))) __bf16 bf16x8;
typedef __attribute__((ext_vector_type(4))) __bf16 bf16x4;
typedef __attribute__((ext_vector_type(4))) float f32x4;

// LDS: K[buf]: 32 keys x 128 d bf16, 256B rows, 16B-chunk XOR swizzle ((key&7)<<4)
//      Vt[buf]: 128 d x 40 keys bf16 (pad 40 -> read banks 2-way free)
#define KS_BYTES 8192
#define VT_BYTES 10240
#define KS_OFF(b) ((b) * KS_BYTES)
#define VT_OFF(b) (2 * KS_BYTES + (b) * VT_BYTES)

static __device__ __forceinline__ bf16x8 cvt8s(const float* __restrict__ p, float s) {
    const f32x4 a = *reinterpret_cast<const f32x4*>(p);
    const f32x4 b = *reinterpret_cast<const f32x4*>(p + 4);
    bf16x8 r;
    r[0] = (__bf16)(a[0] * s); r[1] = (__bf16)(a[1] * s);
    r[2] = (__bf16)(a[2] * s); r[3] = (__bf16)(a[3] * s);
    r[4] = (__bf16)(b[0] * s); r[5] = (__bf16)(b[1] * s);
    r[6] = (__bf16)(b[2] * s); r[7] = (__bf16)(b[3] * s);
    return r;
}

// One wave = 16 q-rows of one head; block = the 4 heads of one kv group (shared K/V).
// Swapped QK^T (S^T = K*Q^T): softmax lane-local + 2 shfl_xor. PV as O^T = V^T*P^T
// with identical A/B k-slot conventions (invariant to HW slot permutation).
// K/V staged once per block into LDS bf16, double-buffered, async-split staging.
__global__ __launch_bounds__(256, 2)
void attn_fwd(const float* __restrict__ Q,
              const float* __restrict__ Kn,
              const float* __restrict__ Vn,
              const float* __restrict__ Kc,
              const float* __restrict__ Vc,
              const int* __restrict__ PT,
              const int* __restrict__ CTX,
              float* __restrict__ O)
{
    __shared__ __align__(16) unsigned char smem[2 * KS_BYTES + 2 * VT_BYTES];

    const int ctx  = CTX[0];                 // 2048
    const int tid  = (int)threadIdx.x;
    const int wave = tid >> 6;
    const int lane = tid & 63;
    const int low  = lane & 15;
    const int hi   = lane >> 4;

    // XCD-friendly mapping: the 8 q-tile blocks of one (b,kvh) share bid%8 -> same XCD L2
    const int bid   = (int)blockIdx.x;
    const int kvh   = bid & 7;
    const int b     = (bid >> 3) & 7;
    const int qtile = bid >> 6;
    const int head  = kvh * GRP + wave;
    const int q0    = qtile * 16;

    const int qtok = b * LQB + q0 + low;
    const float* qrow = Q + (size_t)qtok * (NH * HD) + head * HD;

    bf16x8 qf[4];                            // Q B-fragments, pre-scaled
    #pragma unroll
    for (int c = 0; c < 4; ++c) qf[c] = cvt8s(qrow + 32 * c + 8 * hi, QK_SCALE);

    f32x4 acc[8];
    #pragma unroll
    for (int c = 0; c < 8; ++c) acc[c] = (f32x4){0.f, 0.f, 0.f, 0.f};
    float mrun = -1e30f, lrun = 0.f;

    // staging ids
    const int skey = tid >> 3;               // K: key row 0..31
    const int sc8  = tid & 7;                // K: 16-float col chunk
    const int kxr  = (skey & 7) << 4;
    const int vdc  = tid >> 3;               // V: d-chunk (4 floats) 0..31
    const int vkq  = tid & 7;                // V: key quad 0..7 (keys 4*vkq..+3)

    f32x4 kr[4], vr[4];                      // in-flight staging registers

    const int nsteps = (ctx >> 5) + (q0 >> 5) + 1;

    auto issue_loads = [&](int t0) {
        {   // K row for skey (16 floats starting 16*sc8)
            const float* src; size_t ro;
            const int tok = t0 + skey;
            if (t0 < ctx) {
                const int pg = PT[b * PTSTRIDE + (tok >> 4)];
                src = Kc; ro = ((size_t)pg * 16 + (tok & 15)) * KVROW + kvh * HD;
            } else {
                src = Kn; ro = (size_t)(b * LQB + tok - ctx) * KVROW + kvh * HD;
            }
            const f32x4* p = reinterpret_cast<const f32x4*>(src + ro + 16 * sc8);
            kr[0] = p[0]; kr[1] = p[1]; kr[2] = p[2]; kr[3] = p[3];
        }
        {   // V: 4 consecutive key rows (4-aligned -> same page), 4 d each
            const float* src; size_t ro;
            const int tok0 = t0 + 4 * vkq;
            if (t0 < ctx) {
                const int pg = PT[b * PTSTRIDE + (tok0 >> 4)];
                src = Vc; ro = ((size_t)pg * 16 + (tok0 & 15)) * KVROW + kvh * HD;
            } else {
                src = Vn; ro = (size_t)(b * LQB + tok0 - ctx) * KVROW + kvh * HD;
            }
            const float* base = src + ro + 4 * vdc;
            vr[0] = *reinterpret_cast<const f32x4*>(base);
            vr[1] = *reinterpret_cast<const f32x4*>(base + KVROW);
            vr[2] = *reinterpret_cast<const f32x4*>(base + 2 * KVROW);
            vr[3] = *reinterpret_cast<const f32x4*>(base + 3 * KVROW);
        }
    };

    auto write_tile = [&](int buf) {
        // K: two swizzled 16B chunks (d = 16*sc8 .. +15)
        unsigned char* ks = smem + KS_OFF(buf) + skey * 256;
        bf16x8 c0, c1;
        #pragma unroll
        for (int j = 0; j < 4; ++j) {
            c0[j] = (__bf16)kr[0][j]; c0[j + 4] = (__bf16)kr[1][j];
            c1[j] = (__bf16)kr[2][j]; c1[j + 4] = (__bf16)kr[3][j];
        }
        *reinterpret_cast<bf16x8*>(ks + ((32 * sc8) ^ kxr))      = c0;
        *reinterpret_cast<bf16x8*>(ks + ((32 * sc8 + 16) ^ kxr)) = c1;
        // V transposed: b64 of 4 consecutive keys at one d (bank floor only)
        unsigned char* vt = smem + VT_OFF(buf) + 8 * vkq;
        #pragma unroll
        for (int di = 0; di < 4; ++di) {
            bf16x4 w;
            w[0] = (__bf16)vr[0][di]; w[1] = (__bf16)vr[1][di];
            w[2] = (__bf16)vr[2][di]; w[3] = (__bf16)vr[3][di];
            *reinterpret_cast<bf16x4*>(vt + (4 * vdc + di) * 80) = w;
        }
    };

    issue_loads(0);
    write_tile(0);
    __syncthreads();

    int cur = 0;
    for (int s = 0; s < nsteps; ++s) {
        if (s + 1 < nsteps) issue_loads((s + 1) << 5);   // async: land during compute

        const unsigned char* ks = smem + KS_OFF(cur);
        const unsigned char* vt = smem + VT_OFF(cur);
        const int xr = (low & 7) << 4;

        f32x4 s0 = (f32x4){0.f, 0.f, 0.f, 0.f};
        f32x4 s1 = (f32x4){0.f, 0.f, 0.f, 0.f};
        #pragma unroll
        for (int c = 0; c < 4; ++c) {
            bf16x8 ka = *reinterpret_cast<const bf16x8*>(ks + low * 256 + ((64 * c + 16 * hi) ^ xr));
            bf16x8 kb = *reinterpret_cast<const bf16x8*>(ks + (16 + low) * 256 + ((64 * c + 16 * hi) ^ xr));
            s0 = __builtin_amdgcn_mfma_f32_16x16x32_bf16(ka, qf[c], s0, 0, 0, 0);
            s1 = __builtin_amdgcn_mfma_f32_16x16x32_bf16(kb, qf[c], s1, 0, 0, 0);
        }

        float pmax = fmaxf(fmaxf(fmaxf(s0[0], s0[1]), fmaxf(s0[2], s0[3])),
                           fmaxf(fmaxf(s1[0], s1[1]), fmaxf(s1[2], s1[3])));
        pmax = fmaxf(pmax, __shfl_xor(pmax, 16));
        pmax = fmaxf(pmax, __shfl_xor(pmax, 32));
        const float mnew = fmaxf(mrun, pmax);
        const float corr = __expf(mrun - mnew);
        mrun = mnew;

        float p[8];
        #pragma unroll
        for (int j = 0; j < 4; ++j) {
            p[j]     = __expf(s0[j] - mnew);
            p[j + 4] = __expf(s1[j] - mnew);
        }
        lrun = lrun * corr +
               (((p[0] + p[1]) + (p[2] + p[3])) + ((p[4] + p[5]) + (p[6] + p[7])));

        bf16x8 pf;
        #pragma unroll
        for (int j = 0; j < 8; ++j) pf[j] = (__bf16)p[j];

        #pragma unroll
        for (int c = 0; c < 8; ++c) acc[c] *= corr;

        #pragma unroll
        for (int c = 0; c < 8; ++c) {
            const unsigned char* vrow = vt + (16 * c + low) * 80 + 8 * hi;
            bf16x4 a0 = *reinterpret_cast<const bf16x4*>(vrow);
            bf16x4 a1 = *reinterpret_cast<const bf16x4*>(vrow + 32);
            bf16x8 vf;
            vf[0] = a0[0]; vf[1] = a0[1]; vf[2] = a0[2]; vf[3] = a0[3];
            vf[4] = a1[0]; vf[5] = a1[1]; vf[6] = a1[2]; vf[7] = a1[3];
            acc[c] = __builtin_amdgcn_mfma_f32_16x16x32_bf16(vf, pf, acc[c], 0, 0, 0);
        }

        if (s + 1 < nsteps) write_tile(cur ^ 1);   // regs -> LDS after compute
        __syncthreads();
        cur ^= 1;
    }

    lrun += __shfl_xor(lrun, 16);
    lrun += __shfl_xor(lrun, 32);
    const float inv = 1.0f / lrun;

    float* orow = O + (size_t)qtok * (NH * HD) + head * HD;
    #pragma unroll
    for (int c = 0; c < 8; ++c) {
        f32x4 r = acc[c] * inv;
        *reinterpret_cast<f32x4*>(orow + 16 * c + 4 * hi) = r;
    }
}

extern "C" void kernel_launch(void* const* d_in, const int* in_sizes, int n_in,
                              void* d_out, int out_size, void* d_ws, size_t ws_size,
                              hipStream_t stream) {
    const float* q  = (const float*)d_in[0];
    const float* k  = (const float*)d_in[1];
    const float* v  = (const float*)d_in[2];
    const float* kc = (const float*)d_in[3];
    const float* vc = (const float*)d_in[4];
    const int*   pt = (const int*)d_in[5];
    const int*   cx = (const int*)d_in[6];
    float* out = (float*)d_out;

    attn_fwd<<<dim3(512), dim3(256), 0, stream>>>(q, k, v, kc, vc, pt, cx, out);
}